// Round 1
// baseline (397.344 us; speedup 1.0000x reference)
//
#include <hip/hip_runtime.h>
#include <math.h>

#define B_    8
#define AT_   96
#define NBR_  512
#define NANG_ 125
#define NF_   128
#define NB_   128
#define TN    32
#define NCHUNK 2
#define CROWS (NBR_ / NCHUNK)   // 256 neighbors per block
#define NTI   (CROWS / TN)      // 8 K-tiles per block
#define TSTRIDE 136             // bf16 elems per hs row (pad)
#define JSTRIDE 132             // f32 elems per yjk row (pad)

typedef __attribute__((ext_vector_type(8))) short bf16x8;
typedef __attribute__((ext_vector_type(4))) float f32x4;

// cheap bf16 convert: round-half-up, 2 VALU ops
__device__ __forceinline__ short f2bf(float f) {
    union { float f; unsigned u; } x; x.f = f;
    return (short)((x.u + 0x8000u) >> 16);
}

// shifted softplus on HW transcendentals:
// ssp(x) = ln2 * (log2(1 + exp2(x*log2e)) - 1)
__device__ __forceinline__ float sspf(float x) {
    float p = __builtin_amdgcn_exp2f(x * 1.44269504088896340736f);
    float l = __builtin_amdgcn_logf(1.0f + p);     // v_log_f32 = log2
    return 0.69314718055994530942f * l - 0.69314718055994530942f;
}

// alignment-agnostic 16B load (trip rows are 500B apart -> only 4B aligned)
__device__ __forceinline__ f32x4 ld4u(const float* p) {
    f32x4 v; __builtin_memcpy(&v, p, 16); return v;
}

// 2x f32x4 -> bf16x8 via packed HW convert (RNE)
__device__ __forceinline__ bf16x8 cvt8(f32x4 lo, f32x4 hi) {
    unsigned r0, r1, r2, r3;
    asm("v_cvt_pk_bf16_f32 %0, %1, %2" : "=v"(r0) : "v"(lo.x), "v"(lo.y));
    asm("v_cvt_pk_bf16_f32 %0, %1, %2" : "=v"(r1) : "v"(lo.z), "v"(lo.w));
    asm("v_cvt_pk_bf16_f32 %0, %1, %2" : "=v"(r2) : "v"(hi.x), "v"(hi.y));
    asm("v_cvt_pk_bf16_f32 %0, %1, %2" : "=v"(r3) : "v"(hi.z), "v"(hi.w));
    typedef __attribute__((ext_vector_type(4))) unsigned u32x4;
    u32x4 r = { r0, r1, r2, r3 };
    return __builtin_bit_cast(bf16x8, r);
}

// Fused prep: blocks [0,192) compute y = x@Win for 4 rows each;
// blocks [192,320) pack W1/W2 into MFMA B-fragment order (bf16).
__global__ __launch_bounds__(128) void prep_kernel(
    const float* __restrict__ x, const float* __restrict__ Win,
    const float* __restrict__ W1, const float* __restrict__ W2,
    float* __restrict__ y, short* __restrict__ w1p, short* __restrict__ w2p)
{
    __shared__ float xs[4][NB_];
    int blk = blockIdx.x, tid = threadIdx.x;
    if (blk < 192) {
        int row0 = blk * 4;
        #pragma unroll
        for (int r = 0; r < 4; r++) xs[r][tid] = x[(row0 + r) * NB_ + tid];
        __syncthreads();
        float a0 = 0.f, a1 = 0.f, a2 = 0.f, a3 = 0.f;
        #pragma unroll 8
        for (int k = 0; k < NB_; k++) {
            float w = Win[k * NF_ + tid];
            a0 = fmaf(xs[0][k], w, a0);
            a1 = fmaf(xs[1][k], w, a1);
            a2 = fmaf(xs[2][k], w, a2);
            a3 = fmaf(xs[3][k], w, a3);
        }
        y[(row0 + 0) * NF_ + tid] = a0;
        y[(row0 + 1) * NF_ + tid] = a1;
        y[(row0 + 2) * NF_ + tid] = a2;
        y[(row0 + 3) * NF_ + tid] = a3;
    } else {
        int t = (blk - 192) * 128 + tid;   // [0, 16384)
        int j = t & 7, lane = (t >> 3) & 63, ks = (t >> 9) & 3, ct = t >> 11;
        int k = ks * 32 + (lane >> 4) * 8 + j;
        int n = ct * 16 + (lane & 15);
        w1p[t] = (k < NANG_) ? f2bf(W1[k * NF_ + n]) : (short)0;  // zero-pad K 125..127
        w2p[t] = f2bf(W2[k * NF_ + n]);
    }
}

// One block per (atom, nbr-half). A-fragments of the filternet GEMM1 are
// loaded straight from global (no LDS staging/scatter); W1/W2 fragments
// live in registers; hs/yjk are double-buffered -> 1 barrier per K-tile.
__global__ __launch_bounds__(256, 2) void triple_partial(
    const float* __restrict__ trip,
    const int* __restrict__ nbj, const int* __restrict__ nbk,
    const float* __restrict__ maskg,
    const float* __restrict__ b1g, const float* __restrict__ b2g,
    const float* __restrict__ y, const short* __restrict__ w1p,
    const short* __restrict__ w2p, float* __restrict__ pagg)
{
    __shared__ short hs[2][TN * TSTRIDE];    // 2 x 8704 B
    __shared__ float yjk[2][TN * JSTRIDE];   // 2 x 16896 B

    const int tid = threadIdx.x;
    const int wave = tid >> 6, lane = tid & 63;
    const int quad = lane >> 4, col = lane & 15;
    const int blk = blockIdx.x;
    const int bid = blk >> 1, c = blk & 1;
    const int b = bid / AT_;

    const float* tpc = trip + (long)bid * NBR_ * NANG_ + (long)c * CROWS * NANG_;
    const int nb_base = bid * NBR_ + c * CROWS;

    const int ct0 = 2 * wave, ct1 = 2 * wave + 1;
    const int f0 = ct0 * 16 + col, f1 = ct1 * 16 + col;
    const float bias1_0 = b1g[f0], bias1_1 = b1g[f1];
    const float bias2_0 = b2g[f0], bias2_1 = b2g[f1];

    const int yrow = tid >> 3, ypart = tid & 7;   // yjk staging role
    const bool lastblk = (blk == B_ * AT_ * NCHUNK - 1);

    // ---- W1/W2 MFMA B-fragments into registers (L2-hot, once per block) ----
    bf16x8 w1f0[4], w1f1[4], w2f0[4], w2f1[4];
    #pragma unroll
    for (int ks = 0; ks < 4; ks++) {
        w1f0[ks] = *(const bf16x8*)&w1p[(ct0 * 4 + ks) * 512 + lane * 8];
        w1f1[ks] = *(const bf16x8*)&w1p[(ct1 * 4 + ks) * 512 + lane * 8];
        w2f0[ks] = *(const bf16x8*)&w2p[(ct0 * 4 + ks) * 512 + lane * 8];
        w2f1[ks] = *(const bf16x8*)&w2p[(ct1 * 4 + ks) * 512 + lane * 8];
    }

    // index prefetch for nt=0
    int jj = nbj[nb_base + yrow];
    int kk = nbk[nb_base + yrow];
    float mk = maskg[nb_base + yrow];

    // trip prefetch (nt=0, ks=0): this lane serves rows col and 16+col
    const float* arow = tpc + col * NANG_;
    f32x4 pa0 = ld4u(arow + quad * 8);
    f32x4 pa1 = ld4u(arow + quad * 8 + 4);
    f32x4 pb0 = ld4u(arow + 16 * NANG_ + quad * 8);
    f32x4 pb1 = ld4u(arow + 16 * NANG_ + quad * 8 + 4);

    float accw0 = 0.f, accw1 = 0.f;
    int cur = 0;

    for (int nt = 0; nt < NTI; nt++) {
        // ---- y gathers for this tile (consumed after GEMM1) ----
        const float* yjp = y + (b * AT_ + jj) * NF_ + ypart * 16;
        const float* ykp = y + (b * AT_ + kk) * NF_ + ypart * 16;
        f32x4 j0 = ((const f32x4*)yjp)[0], j1 = ((const f32x4*)yjp)[1];
        f32x4 j2 = ((const f32x4*)yjp)[2], j3 = ((const f32x4*)yjp)[3];
        f32x4 k0 = ((const f32x4*)ykp)[0], k1 = ((const f32x4*)ykp)[1];
        f32x4 k2 = ((const f32x4*)ykp)[2], k3 = ((const f32x4*)ykp)[3];
        const float mc = mk;
        if (nt + 1 < NTI) {    // index prefetch for next tile
            jj = nbj[nb_base + (nt + 1) * TN + yrow];
            kk = nbk[nb_base + (nt + 1) * TN + yrow];
            mk = maskg[nb_base + (nt + 1) * TN + yrow];
        }

        const bool lt = lastblk && (nt == NTI - 1);
        const float* anext = (nt == NTI - 1) ? arow : (arow + TN * NANG_);

        // ---- GEMM1: H = ssp(T @ W1 + b1); A direct from global, depth-1 prefetch ----
        f32x4 d00 = {0,0,0,0}, d01 = {0,0,0,0}, d10 = {0,0,0,0}, d11 = {0,0,0,0};
        #pragma unroll
        for (int ks = 0; ks < 4; ks++) {
            bf16x8 a0 = cvt8(pa0, pa1);
            bf16x8 a1 = cvt8(pb0, pb1);
            // prefetch next fragment (ks+1, or ks=0 of next tile)
            const float* pn = (ks < 3) ? arow : anext;
            const int    ko = (ks < 3) ? ((ks + 1) * 32 + quad * 8) : (quad * 8);
            pa0 = ld4u(pn + ko);
            pa1 = ld4u(pn + ko + 4);
            pb0 = ld4u(pn + 16 * NANG_ + ko);
            // k=125..127 read past row end into the next row (valid floats,
            // multiplied by zero-padded W1) -- except the global last row,
            // where the final 16B load would run 12B past the buffer.
            if (ks == 2 && lt && lane == 63) {
                pb1 = (f32x4){ pn[16 * NANG_ + ko + 4], 0.f, 0.f, 0.f };
            } else {
                pb1 = ld4u(pn + 16 * NANG_ + ko + 4);
            }
            d00 = __builtin_amdgcn_mfma_f32_16x16x32_bf16(a0, w1f0[ks], d00, 0, 0, 0);
            d01 = __builtin_amdgcn_mfma_f32_16x16x32_bf16(a0, w1f1[ks], d01, 0, 0, 0);
            d10 = __builtin_amdgcn_mfma_f32_16x16x32_bf16(a1, w1f0[ks], d10, 0, 0, 0);
            d11 = __builtin_amdgcn_mfma_f32_16x16x32_bf16(a1, w1f1[ks], d11, 0, 0, 0);
        }
        arow = anext;

        // ---- yjk = y_j * y_k * mask (fp32, gathers have landed) ----
        {
            float* d = &yjk[cur][yrow * JSTRIDE + ypart * 16];
            *(f32x4*)(d + 0)  = j0 * k0 * mc;
            *(f32x4*)(d + 4)  = j1 * k1 * mc;
            *(f32x4*)(d + 8)  = j2 * k2 * mc;
            *(f32x4*)(d + 12) = j3 * k3 * mc;
        }
        // ---- ssp + bf16 pack into hs[cur] ----
        #pragma unroll
        for (int r = 0; r < 4; r++) {
            int row0 = quad * 4 + r, row1 = 16 + quad * 4 + r;
            hs[cur][row0 * TSTRIDE + f0] = f2bf(sspf(d00[r] + bias1_0));
            hs[cur][row0 * TSTRIDE + f1] = f2bf(sspf(d01[r] + bias1_1));
            hs[cur][row1 * TSTRIDE + f0] = f2bf(sspf(d10[r] + bias1_0));
            hs[cur][row1 * TSTRIDE + f1] = f2bf(sspf(d11[r] + bias1_1));
        }
        __syncthreads();   // the only barrier per K-tile (double-buffered LDS)

        // ---- GEMM2 + fused conv + aggregation ----
        f32x4 e00 = {0,0,0,0}, e01 = {0,0,0,0}, e10 = {0,0,0,0}, e11 = {0,0,0,0};
        #pragma unroll
        for (int ks = 0; ks < 4; ks++) {
            bf16x8 a0 = *(const bf16x8*)&hs[cur][(     col) * TSTRIDE + ks * 32 + quad * 8];
            bf16x8 a1 = *(const bf16x8*)&hs[cur][(16 + col) * TSTRIDE + ks * 32 + quad * 8];
            e00 = __builtin_amdgcn_mfma_f32_16x16x32_bf16(a0, w2f0[ks], e00, 0, 0, 0);
            e01 = __builtin_amdgcn_mfma_f32_16x16x32_bf16(a0, w2f1[ks], e01, 0, 0, 0);
            e10 = __builtin_amdgcn_mfma_f32_16x16x32_bf16(a1, w2f0[ks], e10, 0, 0, 0);
            e11 = __builtin_amdgcn_mfma_f32_16x16x32_bf16(a1, w2f1[ks], e11, 0, 0, 0);
        }
        #pragma unroll
        for (int r = 0; r < 4; r++) {
            int row0 = quad * 4 + r, row1 = 16 + quad * 4 + r;
            accw0 += (e00[r] + bias2_0) * yjk[cur][row0 * JSTRIDE + f0];
            accw1 += (e01[r] + bias2_1) * yjk[cur][row0 * JSTRIDE + f1];
            accw0 += (e10[r] + bias2_0) * yjk[cur][row1 * JSTRIDE + f0];
            accw1 += (e11[r] + bias2_1) * yjk[cur][row1 * JSTRIDE + f1];
        }
        cur ^= 1;
    }

    // reduce partials across quads; write per-half partial aggregate
    accw0 += __shfl_xor(accw0, 16, 64);
    accw0 += __shfl_xor(accw0, 32, 64);
    accw1 += __shfl_xor(accw1, 16, 64);
    accw1 += __shfl_xor(accw1, 32, 64);
    if (quad == 0) {
        pagg[blk * NF_ + f0] = accw0;
        pagg[blk * NF_ + f1] = accw1;
    }
}

// Sum 2 partials, f2out (ssp), dense, residual.
__global__ __launch_bounds__(128) void finish_kernel(
    const float* __restrict__ x, const float* __restrict__ pagg,
    const float* __restrict__ Wf2, const float* __restrict__ bf2,
    const float* __restrict__ Wd, const float* __restrict__ bd,
    float* __restrict__ out)
{
    __shared__ float aggs[NF_];
    __shared__ float t1s[NF_];
    int bid = blockIdx.x, f = threadIdx.x;
    float a = pagg[(bid * 2 + 0) * NF_ + f] + pagg[(bid * 2 + 1) * NF_ + f];
    aggs[f] = a;
    __syncthreads();
    float acc = 0.f;
    #pragma unroll 8
    for (int k = 0; k < NF_; k++) acc = fmaf(aggs[k], Wf2[k * NB_ + f], acc);
    t1s[f] = sspf(acc + bf2[f]);
    __syncthreads();
    acc = 0.f;
    #pragma unroll 8
    for (int k = 0; k < NB_; k++) acc = fmaf(t1s[k], Wd[k * NB_ + f], acc);
    out[bid * NB_ + f] = x[bid * NB_ + f] + acc + bd[f];
}

extern "C" void kernel_launch(void* const* d_in, const int* in_sizes, int n_in,
                              void* d_out, int out_size, void* d_ws, size_t ws_size,
                              hipStream_t stream) {
    const float* x    = (const float*)d_in[0];
    const float* trip = (const float*)d_in[1];
    const int*   nbj  = (const int*)d_in[2];
    const int*   nbk  = (const int*)d_in[3];
    const float* mask = (const float*)d_in[4];
    const float* W1   = (const float*)d_in[5];
    const float* b1   = (const float*)d_in[6];
    const float* W2   = (const float*)d_in[7];
    const float* b2   = (const float*)d_in[8];
    const float* Win  = (const float*)d_in[9];
    const float* Wf2  = (const float*)d_in[10];
    const float* bf2  = (const float*)d_in[11];
    const float* Wd   = (const float*)d_in[12];
    const float* bd   = (const float*)d_in[13];
    float* out = (float*)d_out;

    char* ws = (char*)d_ws;
    float* y    = (float*)ws;                        // 393216 B
    short* w1p  = (short*)(ws + 393216);             // 32768 B
    short* w2p  = (short*)(ws + 393216 + 32768);     // 32768 B
    float* pagg = (float*)(ws + 393216 + 65536);     // 1536*128*4 = 786432 B

    prep_kernel<<<320, 128, 0, stream>>>(x, Win, W1, W2, y, w1p, w2p);
    triple_partial<<<B_ * AT_ * NCHUNK, 256, 0, stream>>>(trip, nbj, nbk, mask,
        b1, b2, y, w1p, w2p, pagg);
    finish_kernel<<<B_ * AT_, 128, 0, stream>>>(x, pagg, Wf2, bf2, Wd, bd, out);
}

// Round 2
// 347.162 us; speedup vs baseline: 1.1445x; 1.1445x over previous
//
#include <hip/hip_runtime.h>
#include <math.h>

#define B_    8
#define AT_   96
#define NBR_  512
#define NANG_ 125
#define NF_   128
#define NB_   128
#define TN    32
#define NCHUNK 2
#define CROWS (NBR_ / NCHUNK)   // 256 neighbors per block
#define NTI   (CROWS / TN)      // 8 K-tiles per block
#define TSTRIDE 136             // bf16 elems per hs row (16B-aligned rows)
#define YSTRIDE 36              // f32 elems per yjkw row (16B-aligned, odd/4 bank spread)

typedef __attribute__((ext_vector_type(8))) short bf16x8;
typedef __attribute__((ext_vector_type(4))) float f32x4;

#define AS_G __attribute__((address_space(1)))
#define AS_L __attribute__((address_space(3)))

// cheap bf16 convert: round-half-up, 2 VALU ops
__device__ __forceinline__ short f2bf(float f) {
    union { float f; unsigned u; } x; x.f = f;
    return (short)((x.u + 0x8000u) >> 16);
}

// shifted softplus on HW transcendentals:
// ssp(x) = ln2 * (log2(1 + exp2(x*log2e)) - 1)
__device__ __forceinline__ float sspf(float x) {
    float p = __builtin_amdgcn_exp2f(x * 1.44269504088896340736f);
    float l = __builtin_amdgcn_logf(1.0f + p);     // v_log_f32 = log2
    return 0.69314718055994530942f * l - 0.69314718055994530942f;
}

// 2x f32x4 -> bf16x8 via packed HW convert (RNE)
__device__ __forceinline__ bf16x8 cvt8(f32x4 lo, f32x4 hi) {
    unsigned r0, r1, r2, r3;
    asm("v_cvt_pk_bf16_f32 %0, %1, %2" : "=v"(r0) : "v"(lo.x), "v"(lo.y));
    asm("v_cvt_pk_bf16_f32 %0, %1, %2" : "=v"(r1) : "v"(lo.z), "v"(lo.w));
    asm("v_cvt_pk_bf16_f32 %0, %1, %2" : "=v"(r2) : "v"(hi.x), "v"(hi.y));
    asm("v_cvt_pk_bf16_f32 %0, %1, %2" : "=v"(r3) : "v"(hi.z), "v"(hi.w));
    typedef __attribute__((ext_vector_type(4))) unsigned u32x4;
    u32x4 r = { r0, r1, r2, r3 };
    return __builtin_bit_cast(bf16x8, r);
}

// direct global->LDS DMA, one 16B deposit per lane (dest = wave-uniform base + lane*16)
__device__ __forceinline__ void gl_lds16(const void* g, void* l) {
    __builtin_amdgcn_global_load_lds((const AS_G void*)g, (AS_L void*)l, 16, 0, 0);
}

// stage one 32x125-f32 trip tile (16000 B) linearly into LDS
__device__ __forceinline__ void stage_tile(const float* g, float* l, int tid) {
    int wave = tid >> 6;
    const char* gb = (const char*)g + tid * 16;
    char* lb = (char*)l + wave * 1024;
    gl_lds16(gb,          lb);
    gl_lds16(gb + 4096,   lb + 4096);
    gl_lds16(gb + 8192,   lb + 8192);
    if (tid < 232)                     // tail: 3712 B
        gl_lds16(gb + 12288, lb + 12288);
}

// Fused prep: blocks [0,192) compute y = x@Win for 4 rows each;
// blocks [192,320) pack W1/W2 into MFMA B-fragment order (bf16).
__global__ __launch_bounds__(128) void prep_kernel(
    const float* __restrict__ x, const float* __restrict__ Win,
    const float* __restrict__ W1, const float* __restrict__ W2,
    float* __restrict__ y, short* __restrict__ w1p, short* __restrict__ w2p)
{
    __shared__ float xs[4][NB_];
    int blk = blockIdx.x, tid = threadIdx.x;
    if (blk < 192) {
        int row0 = blk * 4;
        #pragma unroll
        for (int r = 0; r < 4; r++) xs[r][tid] = x[(row0 + r) * NB_ + tid];
        __syncthreads();
        float a0 = 0.f, a1 = 0.f, a2 = 0.f, a3 = 0.f;
        #pragma unroll 8
        for (int k = 0; k < NB_; k++) {
            float w = Win[k * NF_ + tid];
            a0 = fmaf(xs[0][k], w, a0);
            a1 = fmaf(xs[1][k], w, a1);
            a2 = fmaf(xs[2][k], w, a2);
            a3 = fmaf(xs[3][k], w, a3);
        }
        y[(row0 + 0) * NF_ + tid] = a0;
        y[(row0 + 1) * NF_ + tid] = a1;
        y[(row0 + 2) * NF_ + tid] = a2;
        y[(row0 + 3) * NF_ + tid] = a3;
    } else {
        int t = (blk - 192) * 128 + tid;   // [0, 16384)
        int j = t & 7, lane = (t >> 3) & 63, ks = (t >> 9) & 3, ct = t >> 11;
        int k = ks * 32 + (lane >> 4) * 8 + j;
        int n = ct * 16 + (lane & 15);
        w1p[t] = (k < NANG_) ? f2bf(W1[k * NF_ + n]) : (short)0;  // zero-pad K 125..127
        w2p[t] = f2bf(W2[k * NF_ + n]);
    }
}

// One block per (atom, nbr-half). Trip tiles DMA'd f32 into LDS
// (global_load_lds, double-buffered); fragments built with cvt_pk from LDS;
// W1/W2 fragments in registers; yjk per-wave (no barrier); hs double-buffered
// -> exactly 1 __syncthreads per K-tile.
__global__ __launch_bounds__(256) void triple_partial(
    const float* __restrict__ trip,
    const int* __restrict__ nbj, const int* __restrict__ nbk,
    const float* __restrict__ maskg,
    const float* __restrict__ b1g, const float* __restrict__ b2g,
    const float* __restrict__ y, const short* __restrict__ w1p,
    const short* __restrict__ w2p, float* __restrict__ pagg)
{
    __shared__ float ldsT[2][4008];          // 32x125 f32 tile + 8-float zero tail
    __shared__ short hs[2][TN * TSTRIDE];    // 2 x 8704 B
    __shared__ float yjkw[4][TN * YSTRIDE];  // per-wave 32x32 (+pad) f32

    const int tid = threadIdx.x;
    const int wave = tid >> 6, lane = tid & 63;
    const int quad = lane >> 4, col = lane & 15;
    const int blk = blockIdx.x;
    const int bid = blk >> 1, c = blk & 1;
    const int b = bid / AT_;

    const float* tpc = trip + (long)bid * NBR_ * NANG_ + (long)c * CROWS * NANG_;
    const int nb_base = bid * NBR_ + c * CROWS;

    const int ct0 = 2 * wave, ct1 = 2 * wave + 1;
    const int f0 = ct0 * 16 + col, f1 = ct1 * 16 + col;
    const float bias1_0 = b1g[f0], bias1_1 = b1g[f1];
    const float bias2_0 = b2g[f0], bias2_1 = b2g[f1];

    // per-wave yjk role: 2 lanes per trip-row, each covering 16 of the
    // wave's 32 filter columns [32*wave, 32*wave+32)
    const int row2 = lane >> 1, h = lane & 1;
    const int ycol = wave * 32 + h * 16;

    // ---- W1/W2 MFMA B-fragments into registers (L2-hot, once per block) ----
    bf16x8 w1f0[4], w1f1[4], w2f0[4], w2f1[4];
    #pragma unroll
    for (int ks = 0; ks < 4; ks++) {
        w1f0[ks] = *(const bf16x8*)&w1p[(ct0 * 4 + ks) * 512 + lane * 8];
        w1f1[ks] = *(const bf16x8*)&w1p[(ct1 * 4 + ks) * 512 + lane * 8];
        w2f0[ks] = *(const bf16x8*)&w2p[(ct0 * 4 + ks) * 512 + lane * 8];
        w2f1[ks] = *(const bf16x8*)&w2p[(ct1 * 4 + ks) * 512 + lane * 8];
    }

    // zero the over-read tails (k=125..127 of last row lands here; x0 weights)
    if (tid < 8) { ldsT[0][4000 + tid] = 0.f; ldsT[1][4000 + tid] = 0.f; }

    // stage tile 0; prefetch tile-0 neighbor indices
    stage_tile(tpc, &ldsT[0][0], tid);
    int jj = nbj[nb_base + row2];
    int kk = nbk[nb_base + row2];
    float mk = maskg[nb_base + row2];

    __syncthreads();   // tile 0 staged (vmcnt drained) + tails visible

    float accw0 = 0.f, accw1 = 0.f;
    int cur = 0;

    for (int nt = 0; nt < NTI; nt++) {
        // ---- issue next-tile DMA into the other buffer ----
        if (nt + 1 < NTI)
            stage_tile(tpc + (nt + 1) * (TN * NANG_), &ldsT[cur ^ 1][0], tid);

        // ---- y gathers for this tile (L2-hot; consumed after GEMM1) ----
        const float* yj = y + (b * AT_ + jj) * NF_ + ycol;
        const float* yk = y + (b * AT_ + kk) * NF_ + ycol;
        f32x4 j0 = ((const f32x4*)yj)[0], j1 = ((const f32x4*)yj)[1];
        f32x4 j2 = ((const f32x4*)yj)[2], j3 = ((const f32x4*)yj)[3];
        f32x4 k0 = ((const f32x4*)yk)[0], k1 = ((const f32x4*)yk)[1];
        f32x4 k2 = ((const f32x4*)yk)[2], k3 = ((const f32x4*)yk)[3];
        const float mc = mk;
        if (nt + 1 < NTI) {    // index prefetch for next tile
            jj = nbj[nb_base + (nt + 1) * TN + row2];
            kk = nbk[nb_base + (nt + 1) * TN + row2];
            mk = maskg[nb_base + (nt + 1) * TN + row2];
        }

        // ---- GEMM1: H = ssp(T @ W1 + b1); A from LDS f32, cvt_pk to bf16 ----
        const float* rA = &ldsT[cur][col * NANG_];
        const float* rB = &ldsT[cur][(16 + col) * NANG_];
        f32x4 d00 = {0,0,0,0}, d01 = {0,0,0,0}, d10 = {0,0,0,0}, d11 = {0,0,0,0};
        #pragma unroll
        for (int ks = 0; ks < 4; ks++) {
            const int ko = ks * 32 + quad * 8;
            float a[8], bfl[8];
            #pragma unroll
            for (int j = 0; j < 8; j++) a[j] = rA[ko + j];
            #pragma unroll
            for (int j = 0; j < 8; j++) bfl[j] = rB[ko + j];
            bf16x8 a0 = cvt8((f32x4){a[0],a[1],a[2],a[3]}, (f32x4){a[4],a[5],a[6],a[7]});
            bf16x8 a1 = cvt8((f32x4){bfl[0],bfl[1],bfl[2],bfl[3]}, (f32x4){bfl[4],bfl[5],bfl[6],bfl[7]});
            d00 = __builtin_amdgcn_mfma_f32_16x16x32_bf16(a0, w1f0[ks], d00, 0, 0, 0);
            d01 = __builtin_amdgcn_mfma_f32_16x16x32_bf16(a0, w1f1[ks], d01, 0, 0, 0);
            d10 = __builtin_amdgcn_mfma_f32_16x16x32_bf16(a1, w1f0[ks], d10, 0, 0, 0);
            d11 = __builtin_amdgcn_mfma_f32_16x16x32_bf16(a1, w1f1[ks], d11, 0, 0, 0);
        }

        // ---- per-wave yjk = y_j * y_k * mask (no cross-wave sync needed) ----
        {
            float* d = &yjkw[wave][row2 * YSTRIDE + h * 16];
            *(f32x4*)(d + 0)  = j0 * k0 * mc;
            *(f32x4*)(d + 4)  = j1 * k1 * mc;
            *(f32x4*)(d + 8)  = j2 * k2 * mc;
            *(f32x4*)(d + 12) = j3 * k3 * mc;
        }
        // ---- ssp + bf16 pack into hs[cur] ----
        #pragma unroll
        for (int r = 0; r < 4; r++) {
            int row0 = quad * 4 + r, row1 = 16 + quad * 4 + r;
            hs[cur][row0 * TSTRIDE + f0] = f2bf(sspf(d00[r] + bias1_0));
            hs[cur][row0 * TSTRIDE + f1] = f2bf(sspf(d01[r] + bias1_1));
            hs[cur][row1 * TSTRIDE + f0] = f2bf(sspf(d10[r] + bias1_0));
            hs[cur][row1 * TSTRIDE + f1] = f2bf(sspf(d11[r] + bias1_1));
        }
        __syncthreads();   // the only barrier per K-tile

        // ---- GEMM2 + fused conv + aggregation ----
        f32x4 e00 = {0,0,0,0}, e01 = {0,0,0,0}, e10 = {0,0,0,0}, e11 = {0,0,0,0};
        #pragma unroll
        for (int ks = 0; ks < 4; ks++) {
            bf16x8 a0 = *(const bf16x8*)&hs[cur][(     col) * TSTRIDE + ks * 32 + quad * 8];
            bf16x8 a1 = *(const bf16x8*)&hs[cur][(16 + col) * TSTRIDE + ks * 32 + quad * 8];
            e00 = __builtin_amdgcn_mfma_f32_16x16x32_bf16(a0, w2f0[ks], e00, 0, 0, 0);
            e01 = __builtin_amdgcn_mfma_f32_16x16x32_bf16(a0, w2f1[ks], e01, 0, 0, 0);
            e10 = __builtin_amdgcn_mfma_f32_16x16x32_bf16(a1, w2f0[ks], e10, 0, 0, 0);
            e11 = __builtin_amdgcn_mfma_f32_16x16x32_bf16(a1, w2f1[ks], e11, 0, 0, 0);
        }
        const float* yw = &yjkw[wave][0];
        #pragma unroll
        for (int r = 0; r < 4; r++) {
            int row0 = quad * 4 + r, row1 = 16 + quad * 4 + r;
            accw0 += (e00[r] + bias2_0) * yw[row0 * YSTRIDE + col];
            accw1 += (e01[r] + bias2_1) * yw[row0 * YSTRIDE + col + 16];
            accw0 += (e10[r] + bias2_0) * yw[row1 * YSTRIDE + col];
            accw1 += (e11[r] + bias2_1) * yw[row1 * YSTRIDE + col + 16];
        }
        cur ^= 1;
    }

    // reduce partials across quads; write per-half partial aggregate
    accw0 += __shfl_xor(accw0, 16, 64);
    accw0 += __shfl_xor(accw0, 32, 64);
    accw1 += __shfl_xor(accw1, 16, 64);
    accw1 += __shfl_xor(accw1, 32, 64);
    if (quad == 0) {
        pagg[blk * NF_ + f0] = accw0;
        pagg[blk * NF_ + f1] = accw1;
    }
}

// Sum 2 partials, f2out (ssp), dense, residual.
__global__ __launch_bounds__(128) void finish_kernel(
    const float* __restrict__ x, const float* __restrict__ pagg,
    const float* __restrict__ Wf2, const float* __restrict__ bf2,
    const float* __restrict__ Wd, const float* __restrict__ bd,
    float* __restrict__ out)
{
    __shared__ float aggs[NF_];
    __shared__ float t1s[NF_];
    int bid = blockIdx.x, f = threadIdx.x;
    float a = pagg[(bid * 2 + 0) * NF_ + f] + pagg[(bid * 2 + 1) * NF_ + f];
    aggs[f] = a;
    __syncthreads();
    float acc = 0.f;
    #pragma unroll 8
    for (int k = 0; k < NF_; k++) acc = fmaf(aggs[k], Wf2[k * NB_ + f], acc);
    t1s[f] = sspf(acc + bf2[f]);
    __syncthreads();
    acc = 0.f;
    #pragma unroll 8
    for (int k = 0; k < NB_; k++) acc = fmaf(t1s[k], Wd[k * NB_ + f], acc);
    out[bid * NB_ + f] = x[bid * NB_ + f] + acc + bd[f];
}

extern "C" void kernel_launch(void* const* d_in, const int* in_sizes, int n_in,
                              void* d_out, int out_size, void* d_ws, size_t ws_size,
                              hipStream_t stream) {
    const float* x    = (const float*)d_in[0];
    const float* trip = (const float*)d_in[1];
    const int*   nbj  = (const int*)d_in[2];
    const int*   nbk  = (const int*)d_in[3];
    const float* mask = (const float*)d_in[4];
    const float* W1   = (const float*)d_in[5];
    const float* b1   = (const float*)d_in[6];
    const float* W2   = (const float*)d_in[7];
    const float* b2   = (const float*)d_in[8];
    const float* Win  = (const float*)d_in[9];
    const float* Wf2  = (const float*)d_in[10];
    const float* bf2  = (const float*)d_in[11];
    const float* Wd   = (const float*)d_in[12];
    const float* bd   = (const float*)d_in[13];
    float* out = (float*)d_out;

    char* ws = (char*)d_ws;
    float* y    = (float*)ws;                        // 393216 B
    short* w1p  = (short*)(ws + 393216);             // 32768 B
    short* w2p  = (short*)(ws + 393216 + 32768);     // 32768 B
    float* pagg = (float*)(ws + 393216 + 65536);     // 1536*128*4 = 786432 B

    prep_kernel<<<320, 128, 0, stream>>>(x, Win, W1, W2, y, w1p, w2p);
    triple_partial<<<B_ * AT_ * NCHUNK, 256, 0, stream>>>(trip, nbj, nbk, mask,
        b1, b2, y, w1p, w2p, pagg);
    finish_kernel<<<B_ * AT_, 128, 0, stream>>>(x, pagg, Wf2, bf2, Wd, bd, out);
}